// Round 1
// baseline (5788.726 us; speedup 1.0000x reference)
//
#include <hip/hip_runtime.h>
#include <hip/hip_bf16.h>

// RSSM scan: B=512, T=64, STOCH=32, DETER=512, HIDDEN=512, ACT=12, EMBED=1024
// out per (b,t): [ostoch32, om32, ostd32, pstoch32, pm32, ps32, deter512] = 704 f32

typedef __attribute__((ext_vector_type(8))) short bf16x8;
typedef __attribute__((ext_vector_type(4))) float f32x4;

static __device__ __forceinline__ short f2b(float x){
  __hip_bfloat16 h = __float2bfloat16(x);
  return *reinterpret_cast<short*>(&h);
}
static __device__ __forceinline__ float b2f(short s){
  __hip_bfloat16 h = *reinterpret_cast<__hip_bfloat16*>(&s);
  return __bfloat162float(h);
}
static __device__ __forceinline__ float softplusf_(float x){
  return (x > 20.f) ? x : log1pf(expf(x));
}

// block reduction (blockDim.x must be power of two); leading sync protects LDS reuse
static __device__ __forceinline__ float bsum(float v, float* red){
  int tid = threadIdx.x;
  __syncthreads();
  red[tid] = v; __syncthreads();
  for(int s = blockDim.x>>1; s>0; s>>=1){
    if(tid < s) red[tid] += red[tid+s];
    __syncthreads();
  }
  return red[0];
}

static __device__ __forceinline__ void stage8f(short* dst, const float* src){
  float4 f0 = *reinterpret_cast<const float4*>(src);
  float4 f1 = *reinterpret_cast<const float4*>(src+4);
  bf16x8 v;
  v[0]=f2b(f0.x); v[1]=f2b(f0.y); v[2]=f2b(f0.z); v[3]=f2b(f0.w);
  v[4]=f2b(f1.x); v[5]=f2b(f1.y); v[6]=f2b(f1.z); v[7]=f2b(f1.w);
  *reinterpret_cast<bf16x8*>(dst) = v;
}

// ---------------- weight transpose/convert (one-time per call) ----------------
// wgruT[n][k]=w_gru[k][n] (1536x1024); wobsDT[n][k]=w_obs[k][n] k<512 (512x512);
// wobsET[n][k]=w_obs[512+k][n] (512x1024); woutT[n][k]=w_out[k][n] (512x512)
__global__ __launch_bounds__(256) void k_wt(const float* __restrict__ wg,
    const float* __restrict__ wo, const float* __restrict__ wou,
    short* __restrict__ wgruT, short* __restrict__ wobsDT,
    short* __restrict__ wobsET, short* __restrict__ woutT){
  int i = blockIdx.x*256 + threadIdx.x;
  if(i < 1572864){ int n = i>>10, k = i&1023; wgruT[i] = f2b(wg[k*1536+n]); return; }
  i -= 1572864;
  if(i < 262144){ int n = i>>9, k = i&511; wobsDT[i] = f2b(wo[k*512+n]); return; }
  i -= 262144;
  if(i < 524288){ int n = i>>10, k = i&1023; wobsET[i] = f2b(wo[(512+k)*512+n]); return; }
  i -= 524288;
  { int n = i>>9, k = i&511; woutT[i] = f2b(wou[k*512+n]); }
}

// ---------------- init: deter0 = tanh(W_init); stoch0 = img_mean(deter0) -----
__global__ __launch_bounds__(512) void k_init(const float* __restrict__ W_init,
    const float* __restrict__ w_out, const float* __restrict__ og, const float* __restrict__ ob,
    const float* __restrict__ w_ims, const float* __restrict__ b_ims,
    float* __restrict__ deter0, float* __restrict__ stoch0){
  __shared__ float d0[512]; __shared__ float red[512]; __shared__ float x2[512];
  int tid = threadIdx.x;
  float d = tanhf(W_init[tid]); d0[tid] = d; deter0[tid] = d; __syncthreads();
  float s = 0.f;
  for(int k=0;k<512;k++) s += d0[k]*w_out[k*512+tid];
  float sum = bsum(s, red);
  float sq  = bsum(s*s, red);
  float mu = sum/512.f, var = sq/512.f - mu*mu;
  float rstd = rsqrtf(var + 1e-3f);
  float xn = (s-mu)*rstd*og[tid] + ob[tid];
  float xs = xn/(1.f+expf(-xn));
  x2[tid] = xs; __syncthreads();
  if(tid < 32){
    float acc = b_ims[tid];
    for(int k=0;k<512;k++) acc += x2[k]*w_ims[k*64+tid];
    stoch0[tid] = acc;
  }
}

// ---------------- t=0 prologue: xdeter row = [x0 | deter0], deterF=deter0 ----
__global__ __launch_bounds__(256) void k_x0(const float* __restrict__ action,
    const float* __restrict__ is_first, const float* __restrict__ w_in,
    const float* __restrict__ ig, const float* __restrict__ ib,
    const float* __restrict__ deter0, const float* __restrict__ stoch0,
    short* __restrict__ xdeter, float* __restrict__ deterF){
  int b = blockIdx.x, tid = threadIdx.x;
  __shared__ float st[32]; __shared__ float al[12]; __shared__ float red[256];
  float f0 = is_first[b*64];
  if(tid < 32) st[tid] = stoch0[tid];
  if(tid < 12) al[tid] = action[b*768 + tid]*(1.f-f0);
  __syncthreads();
  float xp[2];
  for(int i=0;i<2;i++){
    int h = tid + i*256; float a = 0.f;
    for(int k=0;k<32;k++) a += st[k]*w_in[k*512+h];
    for(int k=0;k<12;k++) a += al[k]*w_in[(32+k)*512+h];
    xp[i] = a;
  }
  float sum = bsum(xp[0]+xp[1], red);
  float sq  = bsum(xp[0]*xp[0]+xp[1]*xp[1], red);
  float mu = sum/512.f, var = sq/512.f - mu*mu;
  float rstd = rsqrtf(var + 1e-3f);
  for(int i=0;i<2;i++){
    int h = tid + i*256;
    float xn = (xp[i]-mu)*rstd*ig[h]+ib[h];
    float xs = xn/(1.f+expf(-xn));
    xdeter[b*1024 + h] = f2b(xs);
    xdeter[b*1024 + 512 + h] = f2b(deter0[h]);
    deterF[b*512 + h] = deter0[h];
  }
}

// ---------------- per-step GRU GEMM: parts = [x|deter'] @ w_gru --------------
// M=512 K=1024 N=1536, BM=BN=BK=64, 4 waves (2x2), wave tile 32x32
__global__ __launch_bounds__(256) void k_gru(const short* __restrict__ Axd,
    const short* __restrict__ Bw, float* __restrict__ Cp){
  __shared__ __align__(16) short As[64][72];
  __shared__ __align__(16) short Bs[64][72];
  int tid = threadIdx.x, lane = tid&63, wid = tid>>6;
  int wm = (wid>>1)*32, wn = (wid&1)*32;
  int mP = blockIdx.x*64, nP = blockIdx.y*64;
  f32x4 acc[2][2] = {};
  for(int kt=0; kt<1024; kt+=64){
    #pragma unroll
    for(int c=0;c<2;c++){
      int idx = tid + c*256; int r = idx>>3, kc = (idx&7)*8;
      *(int4*)&As[r][kc] = *(const int4*)&Axd[(mP+r)*1024 + kt + kc];
      *(int4*)&Bs[r][kc] = *(const int4*)&Bw[(nP+r)*1024 + kt + kc];
    }
    __syncthreads();
    #pragma unroll
    for(int ks=0; ks<64; ks+=32){
      int ko = ks + 8*(lane>>4);
      bf16x8 a0 = *(const bf16x8*)&As[wm +      (lane&15)][ko];
      bf16x8 a1 = *(const bf16x8*)&As[wm + 16 + (lane&15)][ko];
      bf16x8 b0 = *(const bf16x8*)&Bs[wn +      (lane&15)][ko];
      bf16x8 b1 = *(const bf16x8*)&Bs[wn + 16 + (lane&15)][ko];
      acc[0][0] = __builtin_amdgcn_mfma_f32_16x16x32_bf16(a0,b0,acc[0][0],0,0,0);
      acc[0][1] = __builtin_amdgcn_mfma_f32_16x16x32_bf16(a0,b1,acc[0][1],0,0,0);
      acc[1][0] = __builtin_amdgcn_mfma_f32_16x16x32_bf16(a1,b0,acc[1][0],0,0,0);
      acc[1][1] = __builtin_amdgcn_mfma_f32_16x16x32_bf16(a1,b1,acc[1][1],0,0,0);
    }
    __syncthreads();
  }
  int r0 = (lane>>4)*4, c0 = lane&15;
  for(int mi=0;mi<2;mi++) for(int ni=0;ni<2;ni++){
    int row = mP + wm + mi*16 + r0, col = nP + wn + ni*16 + c0;
    #pragma unroll
    for(int r=0;r<4;r++) Cp[(row+r)*1536 + col] = acc[mi][ni][r];
  }
}

// ---------------- per-step gates: LN(1536) + GRU update ----------------------
__global__ __launch_bounds__(256) void k_gates(const float* __restrict__ parts,
    const float* __restrict__ gg, const float* __restrict__ gb,
    const float* __restrict__ is_first, const float* __restrict__ deter0,
    float* __restrict__ deterF, short* __restrict__ deterB,
    float* __restrict__ out, int t){
  int b = blockIdx.x, tid = threadIdx.x;
  __shared__ float red[256];
  const float* p = parts + b*1536;
  float v[6]; float s=0.f, sq=0.f;
  #pragma unroll
  for(int k=0;k<6;k++){ v[k] = p[tid + k*256]; s += v[k]; sq += v[k]*v[k]; }
  float sum = bsum(s, red);
  float ssq = bsum(sq, red);
  float mu = sum/1536.f, var = ssq/1536.f - mu*mu;
  float rstd = rsqrtf(var + 1e-3f);
  float f = is_first[b*64 + t];
  for(int jj=0;jj<2;jj++){
    int j = tid + jj*256;
    float xr = (v[jj]  -mu)*rstd*gg[j]       + gb[j];
    float xc = (v[2+jj]-mu)*rstd*gg[512+j]   + gb[512+j];
    float xu = (v[4+jj]-mu)*rstd*gg[1024+j]  + gb[1024+j];
    float r = 1.f/(1.f+expf(-xr));
    float c = tanhf(r*xc);
    float u = 1.f/(1.f+expf(-(xu-1.f)));
    float dp = deterF[b*512+j]*(1.f-f) + deter0[j]*f;
    float dn = u*c + (1.f-u)*dp;
    deterF[b*512+j] = dn;
    deterB[b*512+j] = f2b(dn);
    out[b*45056 + t*704 + 192 + j] = dn;
  }
}

// ---------------- per-step obs GEMM: xopre = [deter_n|embed_t] @ w_obs -------
// M=512 K=1536 N=512
__global__ __launch_bounds__(256) void k_obs(const short* __restrict__ dB,
    const float* __restrict__ emb, const short* __restrict__ WdT,
    const short* __restrict__ WeT, float* __restrict__ xopre, int t){
  __shared__ __align__(16) short As[64][72];
  __shared__ __align__(16) short Bs[64][72];
  int tid = threadIdx.x, lane = tid&63, wid = tid>>6;
  int wm = (wid>>1)*32, wn = (wid&1)*32;
  int mP = blockIdx.x*64, nP = blockIdx.y*64;
  f32x4 acc[2][2] = {};
  for(int kt=0; kt<24; kt++){
    #pragma unroll
    for(int c=0;c<2;c++){
      int idx = tid + c*256; int r = idx>>3, kc = (idx&7)*8;
      if(kt < 8){
        *(int4*)&As[r][kc] = *(const int4*)&dB[(mP+r)*512 + kt*64 + kc];
        *(int4*)&Bs[r][kc] = *(const int4*)&WdT[(nP+r)*512 + kt*64 + kc];
      } else {
        stage8f(&As[r][kc], &emb[(mP+r)*65536 + t*1024 + (kt-8)*64 + kc]);
        *(int4*)&Bs[r][kc] = *(const int4*)&WeT[(nP+r)*1024 + (kt-8)*64 + kc];
      }
    }
    __syncthreads();
    #pragma unroll
    for(int ks=0; ks<64; ks+=32){
      int ko = ks + 8*(lane>>4);
      bf16x8 a0 = *(const bf16x8*)&As[wm +      (lane&15)][ko];
      bf16x8 a1 = *(const bf16x8*)&As[wm + 16 + (lane&15)][ko];
      bf16x8 b0 = *(const bf16x8*)&Bs[wn +      (lane&15)][ko];
      bf16x8 b1 = *(const bf16x8*)&Bs[wn + 16 + (lane&15)][ko];
      acc[0][0] = __builtin_amdgcn_mfma_f32_16x16x32_bf16(a0,b0,acc[0][0],0,0,0);
      acc[0][1] = __builtin_amdgcn_mfma_f32_16x16x32_bf16(a0,b1,acc[0][1],0,0,0);
      acc[1][0] = __builtin_amdgcn_mfma_f32_16x16x32_bf16(a1,b0,acc[1][0],0,0,0);
      acc[1][1] = __builtin_amdgcn_mfma_f32_16x16x32_bf16(a1,b1,acc[1][1],0,0,0);
    }
    __syncthreads();
  }
  int r0 = (lane>>4)*4, c0 = lane&15;
  for(int mi=0;mi<2;mi++) for(int ni=0;ni<2;ni++){
    int row = mP + wm + mi*16 + r0, col = nP + wn + ni*16 + c0;
    #pragma unroll
    for(int r=0;r<4;r++) xopre[(row+r)*512 + col] = acc[mi][ni][r];
  }
}

// ---------------- per-step post: obs LN/silu, ostat, outputs, next x ---------
__global__ __launch_bounds__(256) void k_post(const float* __restrict__ xopre,
    const float* __restrict__ og, const float* __restrict__ ob,
    const float* __restrict__ w_ostat, const float* __restrict__ b_ostat,
    const float* __restrict__ eps_post, const float* __restrict__ is_first,
    const float* __restrict__ action, const float* __restrict__ w_in,
    const float* __restrict__ ig, const float* __restrict__ ib,
    const float* __restrict__ stoch0, const float* __restrict__ deter0,
    const float* __restrict__ deterF, short* __restrict__ xdeter,
    float* __restrict__ out, int t){
  int b = blockIdx.x, tid = threadIdx.x;
  __shared__ float red[256]; __shared__ float xo[512];
  __shared__ float psh[4][64]; __shared__ float sol[64];
  __shared__ float st[32]; __shared__ float al[12];
  float xv[2];
  for(int i=0;i<2;i++) xv[i] = xopre[b*512 + tid + i*256];
  float sum = bsum(xv[0]+xv[1], red);
  float sq  = bsum(xv[0]*xv[0]+xv[1]*xv[1], red);
  float mu = sum/512.f, var = sq/512.f - mu*mu;
  float rstd = rsqrtf(var + 1e-3f);
  for(int i=0;i<2;i++){
    int h = tid + i*256;
    float xn = (xv[i]-mu)*rstd*og[h]+ob[h];
    xo[h] = xn/(1.f+expf(-xn));
  }
  __syncthreads();
  { int p = tid>>6, n = tid&63; float a = 0.f;
    for(int k=p*128; k<p*128+128; k++) a += xo[k]*w_ostat[k*64+n];
    psh[p][n] = a; }
  __syncthreads();
  if(tid < 64) sol[tid] = psh[0][tid]+psh[1][tid]+psh[2][tid]+psh[3][tid] + b_ostat[tid];
  __syncthreads();
  float fn = (t < 63) ? is_first[b*64 + t + 1] : 0.f;
  if(tid < 32){
    float om = sol[tid];
    float osd = softplusf_(sol[32+tid]) + 0.1f;
    float eo = eps_post[(b*64+t)*32 + tid];
    float ost = om + osd*eo;
    int base = b*45056 + t*704;
    out[base+tid] = ost; out[base+32+tid] = om; out[base+64+tid] = osd;
    st[tid] = ost*(1.f-fn) + stoch0[tid]*fn;
  }
  if(tid < 12 && t < 63) al[tid] = action[(b*64+t+1)*12 + tid]*(1.f-fn);
  __syncthreads();
  if(t < 63){
    float xp[2];
    for(int i=0;i<2;i++){
      int h = tid + i*256; float a = 0.f;
      for(int k=0;k<32;k++) a += st[k]*w_in[k*512+h];
      for(int k=0;k<12;k++) a += al[k]*w_in[(32+k)*512+h];
      xp[i] = a;
    }
    float s2 = bsum(xp[0]+xp[1], red);
    float q2 = bsum(xp[0]*xp[0]+xp[1]*xp[1], red);
    float mu2 = s2/512.f, var2 = q2/512.f - mu2*mu2;
    float rstd2 = rsqrtf(var2 + 1e-3f);
    for(int i=0;i<2;i++){
      int h = tid + i*256;
      float xn = (xp[i]-mu2)*rstd2*ig[h]+ib[h];
      float xs = xn/(1.f+expf(-xn));
      xdeter[b*1024 + h] = f2b(xs);
      xdeter[b*1024 + 512 + h] = f2b(deterF[b*512+h]*(1.f-fn) + deter0[h]*fn);
    }
  }
}

// ---------------- deferred img-branch GEMM: x2pre = deter_all @ w_out --------
// M=32768 K=512 N=512; BM=BN=128 BK=64, 4 waves (2x2), wave tile 64x64
__global__ __launch_bounds__(256) void k_img(const float* __restrict__ outp,
    const short* __restrict__ WoT, short* __restrict__ x2pre){
  __shared__ __align__(16) short As[128][72];
  __shared__ __align__(16) short Bs[128][72];
  int tid = threadIdx.x, lane = tid&63, wid = tid>>6;
  int wm = (wid>>1)*64, wn = (wid&1)*64;
  int mP = blockIdx.x*128, nP = blockIdx.y*128;
  f32x4 acc[4][4] = {};
  for(int kt=0; kt<512; kt+=64){
    #pragma unroll
    for(int c=0;c<4;c++){
      int idx = tid + c*256; int r = idx>>3, kc = (idx&7)*8;
      stage8f(&As[r][kc], &outp[(mP+r)*704 + 192 + kt + kc]);
      *(int4*)&Bs[r][kc] = *(const int4*)&WoT[(nP+r)*512 + kt + kc];
    }
    __syncthreads();
    #pragma unroll
    for(int ks=0; ks<64; ks+=32){
      int ko = ks + 8*(lane>>4);
      bf16x8 a[4], b[4];
      #pragma unroll
      for(int i=0;i<4;i++){
        a[i] = *(const bf16x8*)&As[wm + i*16 + (lane&15)][ko];
        b[i] = *(const bf16x8*)&Bs[wn + i*16 + (lane&15)][ko];
      }
      #pragma unroll
      for(int mi=0;mi<4;mi++)
        #pragma unroll
        for(int ni=0;ni<4;ni++)
          acc[mi][ni] = __builtin_amdgcn_mfma_f32_16x16x32_bf16(a[mi],b[ni],acc[mi][ni],0,0,0);
    }
    __syncthreads();
  }
  int r0 = (lane>>4)*4, c0 = lane&15;
  for(int mi=0;mi<4;mi++) for(int ni=0;ni<4;ni++){
    int row = mP + wm + mi*16 + r0, col = nP + wn + ni*16 + c0;
    #pragma unroll
    for(int r=0;r<4;r++) x2pre[(row+r)*512 + col] = f2b(acc[mi][ni][r]);
  }
}

// ---------------- img-branch finish: LN/silu, w_ims, pstoch/pm/ps -----------
__global__ __launch_bounds__(256) void k_imgpost(const short* __restrict__ x2pre,
    const float* __restrict__ og, const float* __restrict__ ob,
    const float* __restrict__ w_ims, const float* __restrict__ b_ims,
    const float* __restrict__ eps_prior, float* __restrict__ out){
  int tid = threadIdx.x;
  int g = tid>>5, l = tid&31;
  int rbase = blockIdx.x*8;
  __shared__ float x2[8][512]; __shared__ float sl[8][64];
  int row = rbase + g;
  float vals[16]; float s=0.f, sq=0.f;
  #pragma unroll
  for(int i=0;i<16;i++){
    int k = l + i*32;
    float v = b2f(x2pre[row*512+k]);
    vals[i] = v; s += v; sq += v*v;
  }
  #pragma unroll
  for(int m=1;m<32;m<<=1){ s += __shfl_xor(s, m); sq += __shfl_xor(sq, m); }
  float mu = s/512.f, var = sq/512.f - mu*mu;
  float rstd = rsqrtf(var + 1e-3f);
  #pragma unroll
  for(int i=0;i<16;i++){
    int k = l + i*32;
    float xn = (vals[i]-mu)*rstd*og[k]+ob[k];
    x2[g][k] = xn/(1.f+expf(-xn));
  }
  __syncthreads();
  { int q = tid>>6, n = tid&63;
    float a0=0.f, a1=0.f;
    for(int k=0;k<512;k++){
      float w = w_ims[k*64+n];
      a0 += x2[q][k]*w; a1 += x2[q+4][k]*w;
    }
    sl[q][n]=a0; sl[q+4][n]=a1; }
  __syncthreads();
  { int r = tid>>5, n = tid&31; int rw = rbase + r;
    float pm = sl[r][n] + b_ims[n];
    float psd = softplusf_(sl[r][n+32] + b_ims[n+32]) + 0.1f;
    float ep = eps_prior[rw*32+n];
    int base = rw*704;
    out[base+96+n] = pm + psd*ep; out[base+128+n] = pm; out[base+160+n] = psd; }
}

extern "C" void kernel_launch(void* const* d_in, const int* in_sizes, int n_in,
                              void* d_out, int out_size, void* d_ws, size_t ws_size,
                              hipStream_t stream) {
  const float* embed     = (const float*)d_in[0];
  const float* action    = (const float*)d_in[1];
  const float* is_first  = (const float*)d_in[2];
  const float* eps_prior = (const float*)d_in[3];
  const float* eps_post  = (const float*)d_in[4];
  const float* W_init    = (const float*)d_in[5];
  const float* w_in      = (const float*)d_in[6];
  const float* ln_in_g   = (const float*)d_in[7];
  const float* ln_in_b   = (const float*)d_in[8];
  const float* w_gru     = (const float*)d_in[9];
  const float* ln_gru_g  = (const float*)d_in[10];
  const float* ln_gru_b  = (const float*)d_in[11];
  const float* w_out     = (const float*)d_in[12];
  const float* ln_out_g  = (const float*)d_in[13];
  const float* ln_out_b  = (const float*)d_in[14];
  const float* w_ims     = (const float*)d_in[15];
  const float* b_ims     = (const float*)d_in[16];
  const float* w_obs     = (const float*)d_in[17];
  const float* ln_obs_g  = (const float*)d_in[18];
  const float* ln_obs_b  = (const float*)d_in[19];
  const float* w_ostat   = (const float*)d_in[20];
  const float* b_ostat   = (const float*)d_in[21];
  float* out = (float*)d_out;
  char* ws = (char*)d_ws;

  short* wgruT  = (short*)(ws + 0);
  short* wobsDT = (short*)(ws + 3145728);
  short* wobsET = (short*)(ws + 3670016);
  short* woutT  = (short*)(ws + 4718592);
  float* deter0 = (float*)(ws + 5242880);
  float* stoch0 = (float*)(ws + 5244928);
  short* xdeter = (short*)(ws + 5245184);
  float* parts  = (float*)(ws + 6293760);
  float* deterF = (float*)(ws + 9439488);
  short* deterB = (short*)(ws + 10488064);
  float* xopre  = (float*)(ws + 11012352);
  short* x2pre  = (short*)(ws + 12060928);
  // total ws use: 45,615,360 bytes

  dim3 blk(256);
  hipLaunchKernelGGL(k_wt, dim3(10240), blk, 0, stream,
                     w_gru, w_obs, w_out, wgruT, wobsDT, wobsET, woutT);
  hipLaunchKernelGGL(k_init, dim3(1), dim3(512), 0, stream,
                     W_init, w_out, ln_out_g, ln_out_b, w_ims, b_ims, deter0, stoch0);
  hipLaunchKernelGGL(k_x0, dim3(512), blk, 0, stream,
                     action, is_first, w_in, ln_in_g, ln_in_b, deter0, stoch0, xdeter, deterF);
  for(int t=0; t<64; t++){
    hipLaunchKernelGGL(k_gru, dim3(8,24), blk, 0, stream, xdeter, wgruT, parts);
    hipLaunchKernelGGL(k_gates, dim3(512), blk, 0, stream,
                       parts, ln_gru_g, ln_gru_b, is_first, deter0, deterF, deterB, out, t);
    hipLaunchKernelGGL(k_obs, dim3(8,8), blk, 0, stream,
                       deterB, embed, wobsDT, wobsET, xopre, t);
    hipLaunchKernelGGL(k_post, dim3(512), blk, 0, stream,
                       xopre, ln_obs_g, ln_obs_b, w_ostat, b_ostat, eps_post, is_first,
                       action, w_in, ln_in_g, ln_in_b, stoch0, deter0, deterF, xdeter, out, t);
  }
  hipLaunchKernelGGL(k_img, dim3(256,4), blk, 0, stream, out, woutT, x2pre);
  hipLaunchKernelGGL(k_imgpost, dim3(4096), blk, 0, stream,
                     x2pre, ln_out_g, ln_out_b, w_ims, b_ims, eps_prior, out);
}